// Round 7
// baseline (283.096 us; speedup 1.0000x reference)
//
#include <hip/hip_runtime.h>
#include <stdint.h>

// ---------- types ----------
typedef __attribute__((ext_vector_type(8)))  short          short8;   // 8 x bf16 bits (4 VGPR)
typedef __attribute__((ext_vector_type(8)))  unsigned short u16x8;
typedef __attribute__((ext_vector_type(4)))  unsigned short u16x4;
typedef __attribute__((ext_vector_type(4)))  float          f32x4;
typedef __attribute__((ext_vector_type(16))) float          f32x16;

__device__ __forceinline__ unsigned short f2bf(float x) {
  unsigned int u = __float_as_uint(x);
  u += 0x7fffu + ((u >> 16) & 1u);           // round-to-nearest-even
  return (unsigned short)(u >> 16);
}
__device__ __forceinline__ float bf2f(unsigned short b) {
  return __uint_as_float(((unsigned int)b) << 16);
}

// MFMA via inline asm (gfx950 unified VGPR file)
__device__ __forceinline__ void mfma16(f32x4& c, short8 a, short8 b) {
  asm volatile("v_mfma_f32_16x16x32_bf16 %0, %1, %2, %0" : "+v"(c) : "v"(a), "v"(b));
}
__device__ __forceinline__ void mfma32(f32x16& c, short8 a, short8 b) {
  asm volatile("v_mfma_f32_32x32x16_bf16 %0, %1, %2, %0" : "+v"(c) : "v"(a), "v"(b));
}

// ---------- 1) split x (fp32 -> hi/lo bf16) ----------
__global__ void split_x_kernel(const float4* __restrict__ x,
                               ushort4* __restrict__ xh, ushort4* __restrict__ xl, int n4) {
  int stride = gridDim.x * blockDim.x;
  for (int i = blockIdx.x * blockDim.x + threadIdx.x; i < n4; i += stride) {
    float4 v = x[i];
    ushort4 h, l;
    h.x = f2bf(v.x); l.x = f2bf(v.x - bf2f(h.x));
    h.y = f2bf(v.y); l.y = f2bf(v.y - bf2f(h.y));
    h.z = f2bf(v.z); l.z = f2bf(v.z - bf2f(h.z));
    h.w = f2bf(v.w); l.w = f2bf(v.w - bf2f(h.w));
    xh[i] = h; xl[i] = l;
  }
}

// ---------- 2) weight transpose + split: W[k][n] fp32 -> WT[n][k] bf16 hi/lo ----------
__global__ void wsplit_kernel(const float* __restrict__ Wq, const float* __restrict__ Wk,
                              const float* __restrict__ Wv, const float* __restrict__ Wo,
                              unsigned short* qh, unsigned short* ql,
                              unsigned short* kh, unsigned short* kl,
                              unsigned short* vh, unsigned short* oh) {
  __shared__ float tile[32][33];
  int z = blockIdx.z;
  const float* W = (z == 0) ? Wq : (z == 1) ? Wk : (z == 2) ? Wv : Wo;
  unsigned short* Oh = (z == 0) ? qh : (z == 1) ? kh : (z == 2) ? vh : oh;
  unsigned short* Ol = (z == 0) ? ql : (z == 1) ? kl : nullptr;
  int k0 = blockIdx.y * 32, n0 = blockIdx.x * 32;
  int tx = threadIdx.x & 31, ty = threadIdx.x >> 5;  // 32 x 8
#pragma unroll
  for (int j = 0; j < 4; ++j)
    tile[ty + 8 * j][tx] = W[(size_t)(k0 + ty + 8 * j) * 1024 + n0 + tx];
  __syncthreads();
#pragma unroll
  for (int j = 0; j < 4; ++j) {
    float v = tile[tx][ty + 8 * j];
    unsigned short h = f2bf(v);
    size_t idx = (size_t)(n0 + ty + 8 * j) * 1024 + k0 + tx;
    Oh[idx] = h;
    if (Ol) Ol[idx] = f2bf(v - bf2f(h));
  }
}

// ---------- 3) GEMM: C[M,N] = A[M,K] * B^T[N,K] + bias ----------
// NSPLIT: 1 = hi only, 3 = hi*hi + hi*lo + lo*hi (split-bf16 ~ fp32 accuracy)
// OUTMODE: 0 = bf16, 1 = bf16 hi/lo pair, 2 = fp32
template <int NSPLIT, int OUTMODE>
__global__ __launch_bounds__(256)
void gemm_kernel(const unsigned short* __restrict__ Ah, const unsigned short* __restrict__ Al,
                 const unsigned short* __restrict__ Bh, const unsigned short* __restrict__ Bl,
                 const float* __restrict__ bias,
                 unsigned short* __restrict__ Ch, unsigned short* __restrict__ Cl,
                 float* __restrict__ Cf, int M, int N, int K) {
  constexpr int NT = (NSPLIT == 3) ? 4 : 2;
  __shared__ unsigned short smem[NT * 8192];          // tiles of 128 rows x 64 k (16KB each)
  unsigned short* sAh = smem;
  unsigned short* sBh = smem + 8192;
  unsigned short* sAl = (NSPLIT == 3) ? smem + 2 * 8192 : smem;
  unsigned short* sBl = (NSPLIT == 3) ? smem + 3 * 8192 : smem;

  int t = threadIdx.x;
  int wid = t >> 6, l = t & 63;
  int wm = wid >> 1, wn = wid & 1;                    // 2x2 waves, 64x64 each
  int bm = blockIdx.y * 128, bn = blockIdx.x * 128;

  f32x4 acc[4][4] = {};

  for (int k0 = 0; k0 < K; k0 += 64) {
    u16x8 ra_h[4], rb_h[4], ra_l[4], rb_l[4];
#pragma unroll
    for (int r = 0; r < 4; ++r) {
      int o = (r * 256 + t) << 4;                     // byte offset in 16KB tile
      int row = o >> 7;                               // 128B rows (64 bf16)
      int col = (o & 127) >> 1;                       // element col
      size_t gA = (size_t)(bm + row) * K + k0 + col;
      size_t gB = (size_t)(bn + row) * K + k0 + col;
      ra_h[r] = *(const u16x8*)(Ah + gA);
      rb_h[r] = *(const u16x8*)(Bh + gB);
      if (NSPLIT == 3) {
        ra_l[r] = *(const u16x8*)(Al + gA);
        rb_l[r] = *(const u16x8*)(Bl + gB);
      }
    }
    __syncthreads();                                  // previous compute done
#pragma unroll
    for (int r = 0; r < 4; ++r) {
      int o = (r * 256 + t) << 4;
      int row = o >> 7;
      int d = (o ^ ((row & 7) << 4)) >> 1;            // XOR swizzle (bank-conflict fix)
      *(u16x8*)(sAh + d) = ra_h[r];
      *(u16x8*)(sBh + d) = rb_h[r];
      if (NSPLIT == 3) {
        *(u16x8*)(sAl + d) = ra_l[r];
        *(u16x8*)(sBl + d) = rb_l[r];
      }
    }
    __syncthreads();
#pragma unroll
    for (int kh = 0; kh < 2; ++kh) {
      short8 afh[4], bfh[4], afl[4], bfl[4];
#pragma unroll
      for (int m = 0; m < 4; ++m) {
        int row = wm * 64 + m * 16 + (l & 15);
        int cb = (((l >> 4) * 16 + kh * 64) ^ ((row & 7) << 4)) >> 1;
        afh[m] = *(const short8*)(sAh + row * 64 + cb);
        if (NSPLIT == 3) afl[m] = *(const short8*)(sAl + row * 64 + cb);
      }
#pragma unroll
      for (int n = 0; n < 4; ++n) {
        int row = wn * 64 + n * 16 + (l & 15);
        int cb = (((l >> 4) * 16 + kh * 64) ^ ((row & 7) << 4)) >> 1;
        bfh[n] = *(const short8*)(sBh + row * 64 + cb);
        if (NSPLIT == 3) bfl[n] = *(const short8*)(sBl + row * 64 + cb);
      }
#pragma unroll
      for (int m = 0; m < 4; ++m)
#pragma unroll
        for (int n = 0; n < 4; ++n) {
          mfma16(acc[m][n], afh[m], bfh[n]);
          if (NSPLIT == 3) {
            mfma16(acc[m][n], afh[m], bfl[n]);
            mfma16(acc[m][n], afl[m], bfh[n]);
          }
        }
    }
  }
  // epilogue: C row = (l>>4)*4 + r, col = l&15 (guide-verified C/D layout)
#pragma unroll
  for (int m = 0; m < 4; ++m) {
    int grow0 = bm + wm * 64 + m * 16 + (l >> 4) * 4;
#pragma unroll
    for (int n = 0; n < 4; ++n) {
      int gcol = bn + wn * 64 + n * 16 + (l & 15);
      float bs = bias[gcol];
#pragma unroll
      for (int r = 0; r < 4; ++r) {
        float v = acc[m][n][r] + bs;
        size_t idx = (size_t)(grow0 + r) * N + gcol;
        if (OUTMODE == 2) {
          Cf[idx] = v;
        } else {
          unsigned short hv = f2bf(v);
          Ch[idx] = hv;
          if (OUTMODE == 1) Cl[idx] = f2bf(v - bf2f(hv));
        }
      }
    }
  }
}

// ---------- 4) V transpose: V[8192][1024] -> VT[1024][8192] (bf16) ----------
__global__ void vtrans_kernel(const unsigned short* __restrict__ V, unsigned short* __restrict__ VT) {
  __shared__ unsigned short tile[64][65];
  int g0 = blockIdx.x * 64, n0 = blockIdx.y * 64;
  int tx = threadIdx.x & 63, ty = threadIdx.x >> 6;   // 64 x 4
#pragma unroll
  for (int j = 0; j < 16; ++j)
    tile[ty + 4 * j][tx] = V[(size_t)(g0 + ty + 4 * j) * 1024 + n0 + tx];
  __syncthreads();
#pragma unroll
  for (int j = 0; j < 16; ++j)
    VT[(size_t)(n0 + ty + 4 * j) * 8192 + g0 + tx] = tile[tx][ty + 4 * j];
}

// ---------- 5) fused attention: 2-wave blocks, LDS K/V staging, in-register P exchange ----------
// grid = (bh=128, qblock=16): XCD-local K/V (id%8 = bh%8). 2048 blocks = 8/CU for
// latency hiding + tail balance (ntiles is prefix-dependent). P->B-frag now a pure
// register exchange: one __shfl_xor(32) per word-pair + selects (plds round-trip gone).
__global__ __launch_bounds__(128)
void attn_kernel(const unsigned short* __restrict__ Qh, const unsigned short* __restrict__ Ql,
                 const unsigned short* __restrict__ Kh,
                 const unsigned short* __restrict__ VT, const int* __restrict__ prefix,
                 unsigned short* __restrict__ AOh) {
  const float NEG = -3.0e38f;
  const float L2E = 1.4426950408889634f;
  __shared__ unsigned short sKh[2][32][66];           // 66 shorts = 33 dwords (odd stride)
  __shared__ unsigned short sV [2][64][34];           // V^T tile [d][k], 17-dword stride

  int bh = blockIdx.x;
  int b = bh >> 4, h = bh & 15;
  int t = threadIdx.x, wid = t >> 6, l = t & 63;
  int qb0 = blockIdx.y * 64;
  int qb = qb0 + wid * 32;
  int P = prefix[b];
  int lq = l & 31, g = l >> 5;
  int q = qb + lq;
  bool qfull = (q < P);
  bool allfull = (P >= qb + 32);                      // wave-uniform: every row full

  // hoist Q^T B-frags (lane = q column), hi/lo
  short8 bqh[4], bql[4];
  {
    size_t base = (size_t)(b * 1024 + q) * 1024 + h * 64 + g * 8;
#pragma unroll
    for (int c = 0; c < 4; ++c) {
      bqh[c] = *(const short8*)(Qh + base + c * 16);
      bql[c] = *(const short8*)(Ql + base + c * 16);
    }
  }

  const unsigned short* KhB = Kh + (size_t)b * 1024 * 1024 + h * 64;
  const unsigned short* VTB = VT + (size_t)(h * 64) * 8192 + b * 1024;

  // staging coords (128 threads): K 32x64 (2 row-passes), V^T 64x32 (2 row-passes)
  int srow = t >> 3, scol = (t & 7) * 8;              // srow 0..15, +16
  int vrow = t >> 2, vcol = (t & 3) * 8;              // vrow 0..31, +32

  int kt0 = (qb0 >= P) ? qb0 : 0;                     // block-uniform start
  int ntiles = (1024 - kt0) >> 5;

  f32x16 o0 = {}, o1 = {};                            // O^T: d rows 0..31 / 32..63, col q
  float mrun = 0.0f, lrun = 0.f;

  u16x8 rkh0, rkh1, rv0, rv1;
  // prologue: stage tile 0
  rkh0 = *(const u16x8*)(KhB + (size_t)(kt0 + srow) * 1024 + scol);
  rkh1 = *(const u16x8*)(KhB + (size_t)(kt0 + srow + 16) * 1024 + scol);
  rv0  = *(const u16x8*)(VTB + (size_t)vrow * 8192 + kt0 + vcol);
  rv1  = *(const u16x8*)(VTB + (size_t)(vrow + 32) * 8192 + kt0 + vcol);
  *(u16x8*)&sKh[0][srow][scol]      = rkh0;
  *(u16x8*)&sKh[0][srow + 16][scol] = rkh1;
  *(u16x8*)&sV [0][vrow][vcol]      = rv0;
  *(u16x8*)&sV [0][vrow + 32][vcol] = rv1;
  __syncthreads();

  int cur = 0;
  for (int i = 0; i < ntiles; ++i) {
    int kt = kt0 + i * 32;
    bool more = (i + 1 < ntiles);
    if (more) {                                       // issue next tile's loads early (T14)
      int ktn = kt + 32;
      rkh0 = *(const u16x8*)(KhB + (size_t)(ktn + srow) * 1024 + scol);
      rkh1 = *(const u16x8*)(KhB + (size_t)(ktn + srow + 16) * 1024 + scol);
      rv0  = *(const u16x8*)(VTB + (size_t)vrow * 8192 + ktn + vcol);
      rv1  = *(const u16x8*)(VTB + (size_t)(vrow + 32) * 8192 + ktn + vcol);
    }

    // wave-uniform: tile contributes nothing for this wave's q-rows
    bool wave_dead = (qb >= P) && (kt + 31 < qb);
    if (!wave_dead) {
      // ---- QK^T on buf cur ----
      f32x16 s = {};
      __builtin_amdgcn_s_setprio(1);
#pragma unroll
      for (int c = 0; c < 4; ++c) {
        short8 ah = *(const short8*)&sKh[cur][lq][g * 8 + c * 16];
        mfma32(s, ah, bqh[c]);
        mfma32(s, ah, bql[c]);
      }
      __builtin_amdgcn_s_setprio(0);

      // mask: only the diagonal tile (kt == qb, not all-full) needs per-element work
      float p[16];
      if (allfull || kt > qb) {
#pragma unroll
        for (int r = 0; r < 16; ++r) p[r] = s[r];
      } else {
#pragma unroll
        for (int r = 0; r < 16; ++r) {
          int k = kt + (r & 3) + 8 * (r >> 2) + 4 * g;
          p[r] = (qfull || k >= q) ? s[r] : NEG;
        }
      }
      // tree max
      float m01 = fmaxf(p[0], p[1]),  m23 = fmaxf(p[2], p[3]);
      float m45 = fmaxf(p[4], p[5]),  m67 = fmaxf(p[6], p[7]);
      float m89 = fmaxf(p[8], p[9]),  mab = fmaxf(p[10], p[11]);
      float mcd = fmaxf(p[12], p[13]), mef = fmaxf(p[14], p[15]);
      float tmax = fmaxf(fmaxf(fmaxf(m01, m23), fmaxf(m45, m67)),
                         fmaxf(fmaxf(m89, mab), fmaxf(mcd, mef)));
      tmax = fmaxf(tmax, __shfl_xor(tmax, 32));
      // defer-max (T13): rescale only when max grew past THR=8
      if (!__all(tmax - mrun <= 8.0f)) {
        float mnew = fmaxf(mrun, tmax);
        float al = exp2f((mrun - mnew) * L2E);
        lrun *= al; o0 *= al; o1 *= al;
        mrun = mnew;
      }
#pragma unroll
      for (int r = 0; r < 16; ++r)
        p[r] = exp2f((p[r] - mrun) * L2E);            // masked: exp2(~-3e38) == 0
      // tree sum
      float s01 = p[0] + p[1],  s23 = p[2] + p[3],  s45 = p[4] + p[5],  s67 = p[6] + p[7];
      float s89 = p[8] + p[9],  sab = p[10] + p[11], scd = p[12] + p[13], sef = p[14] + p[15];
      float psum = ((s01 + s23) + (s45 + s67)) + ((s89 + sab) + (scd + sef));
      psum += __shfl_xor(psum, 32);
      lrun += psum;

      // P -> PV B-frags fully in-register:
      //   lane (lq,g) holds k = (r&3)+8*(r>>2)+4*g; B-frag needs k = [16*frag +] g*8+j.
      //   cvt_pk word pairs (w_lo, w_hi); one shfl_xor(32) per pair rebuilds both words:
      //   g0 keeps w_lo & receives partner's w_lo for the hi word; g1 receives partner's
      //   w_hi for the lo word & keeps w_hi.  (index-verified against the plds layout)
      unsigned int w0, w1, w2, w3, w4, w5, w6, w7;
      asm("v_cvt_pk_bf16_f32 %0, %1, %2" : "=v"(w0) : "v"(p[0]),  "v"(p[1]));
      asm("v_cvt_pk_bf16_f32 %0, %1, %2" : "=v"(w1) : "v"(p[2]),  "v"(p[3]));
      asm("v_cvt_pk_bf16_f32 %0, %1, %2" : "=v"(w2) : "v"(p[4]),  "v"(p[5]));
      asm("v_cvt_pk_bf16_f32 %0, %1, %2" : "=v"(w3) : "v"(p[6]),  "v"(p[7]));
      asm("v_cvt_pk_bf16_f32 %0, %1, %2" : "=v"(w4) : "v"(p[8]),  "v"(p[9]));
      asm("v_cvt_pk_bf16_f32 %0, %1, %2" : "=v"(w5) : "v"(p[10]), "v"(p[11]));
      asm("v_cvt_pk_bf16_f32 %0, %1, %2" : "=v"(w6) : "v"(p[12]), "v"(p[13]));
      asm("v_cvt_pk_bf16_f32 %0, %1, %2" : "=v"(w7) : "v"(p[14]), "v"(p[15]));
      {
        unsigned int v0 = g ? w0 : w2, r0 = __shfl_xor(v0, 32);
        unsigned int v1 = g ? w1 : w3, r1 = __shfl_xor(v1, 32);
        unsigned int v4 = g ? w4 : w6, r4 = __shfl_xor(v4, 32);
        unsigned int v5 = g ? w5 : w7, r5 = __shfl_xor(v5, 32);
        unsigned int n0 = g ? r0 : w0, n2 = g ? w2 : r0;
        unsigned int n1 = g ? r1 : w1, n3 = g ? w3 : r1;
        unsigned int n4 = g ? r4 : w4, n6 = g ? w6 : r4;
        unsigned int n5 = g ? r5 : w5, n7 = g ? w7 : r5;
        w0 = n0; w1 = n1; w2 = n2; w3 = n3; w4 = n4; w5 = n5; w6 = n6; w7 = n7;
      }
      union { unsigned int u[4]; short8 v; } B0, B1;
      B0.u[0] = w0; B0.u[1] = w1; B0.u[2] = w2; B0.u[3] = w3;   // k = kt + g*8 + 0..7
      B1.u[0] = w4; B1.u[1] = w5; B1.u[2] = w6; B1.u[3] = w7;   // k = kt + 16 + g*8 + 0..7

      // O^T += V^T * P^T (A-frags from staged sV)
      short8 va00 = *(const short8*)&sV[cur][lq][g * 8];
      short8 va01 = *(const short8*)&sV[cur][lq][16 + g * 8];
      short8 va10 = *(const short8*)&sV[cur][32 + lq][g * 8];
      short8 va11 = *(const short8*)&sV[cur][32 + lq][16 + g * 8];
      __builtin_amdgcn_s_setprio(1);
      mfma32(o0, va00, B0.v);
      mfma32(o0, va01, B1.v);
      mfma32(o1, va10, B0.v);
      mfma32(o1, va11, B1.v);
      __builtin_amdgcn_s_setprio(0);
    }

    __syncthreads();                                  // all waves done reading buf cur
    if (more) {
      *(u16x8*)&sKh[cur ^ 1][srow][scol]      = rkh0; // write-late
      *(u16x8*)&sKh[cur ^ 1][srow + 16][scol] = rkh1;
      *(u16x8*)&sV [cur ^ 1][vrow][vcol]      = rv0;
      *(u16x8*)&sV [cur ^ 1][vrow + 32][vcol] = rv1;
    }
    __syncthreads();                                  // next buf ready
    cur ^= 1;
  }

  // write AO (bf16) in the reference's scrambled layout:
  // AO[b, h*64 + q/16, (q%16)*64 + d]; d = (r&3) + 8*(r>>2) + 4*g -> vectorized per quad
  float inv = 1.0f / lrun;
  size_t obase = (size_t)(b * 1024 + h * 64 + (q >> 4)) * 1024 + (q & 15) * 64;
#pragma unroll
  for (int tt = 0; tt < 4; ++tt) {
    u16x4 w0, w1;
#pragma unroll
    for (int j = 0; j < 4; ++j) {
      w0[j] = f2bf(o0[4 * tt + j] * inv);
      w1[j] = f2bf(o1[4 * tt + j] * inv);
    }
    *(u16x4*)(AOh + obase + 8 * tt + 4 * g)      = w0;
    *(u16x4*)(AOh + obase + 32 + 8 * tt + 4 * g) = w1;
  }
}

// ---------- launch ----------
extern "C" void kernel_launch(void* const* d_in, const int* in_sizes, int n_in,
                              void* d_out, int out_size, void* d_ws, size_t ws_size,
                              hipStream_t stream) {
  (void)in_sizes; (void)n_in; (void)out_size;
  const float* x      = (const float*)d_in[0];
  const int*   prefix = (const int*)d_in[1];
  const float* Wq = (const float*)d_in[2];
  const float* bq = (const float*)d_in[3];
  const float* Wk = (const float*)d_in[4];
  const float* bk = (const float*)d_in[5];
  const float* Wv = (const float*)d_in[6];
  const float* bv = (const float*)d_in[7];
  const float* Wo = (const float*)d_in[8];
  const float* bo = (const float*)d_in[9];
  float* out = (float*)d_out;

  const size_t MBY = 1ull << 20;
  if (ws_size < 144 * MBY) return;
  char* ws = (char*)d_ws;
  unsigned short* xh  = (unsigned short*)(ws + 0 * MBY);
  unsigned short* xl  = (unsigned short*)(ws + 16 * MBY);
  unsigned short* wqh = (unsigned short*)(ws + 32 * MBY);
  unsigned short* wql = (unsigned short*)(ws + 34 * MBY);
  unsigned short* wkh = (unsigned short*)(ws + 36 * MBY);
  unsigned short* wkl = (unsigned short*)(ws + 38 * MBY);
  unsigned short* wvh = (unsigned short*)(ws + 40 * MBY);
  unsigned short* woh = (unsigned short*)(ws + 44 * MBY);
  unsigned short* Qh  = (unsigned short*)(ws + 48 * MBY);
  unsigned short* Ql  = (unsigned short*)(ws + 64 * MBY);
  unsigned short* Kh  = (unsigned short*)(ws + 80 * MBY);
  unsigned short* V   = (unsigned short*)(ws + 112 * MBY);
  unsigned short* VT  = (unsigned short*)(ws + 128 * MBY);
  unsigned short* AOh = V;    // V dead after vtrans

  split_x_kernel<<<1024, 256, 0, stream>>>((const float4*)x, (ushort4*)xh, (ushort4*)xl,
                                           8192 * 1024 / 4);
  wsplit_kernel<<<dim3(32, 32, 4), 256, 0, stream>>>(Wq, Wk, Wv, Wo,
                                                     wqh, wql, wkh, wkl, wvh, woh);
  gemm_kernel<3, 1><<<dim3(8, 64), 256, 0, stream>>>(xh, xl, wqh, wql, bq, Qh, Ql, nullptr,
                                                     8192, 1024, 1024);
  gemm_kernel<3, 0><<<dim3(8, 64), 256, 0, stream>>>(xh, xl, wkh, wkl, bk, Kh, nullptr, nullptr,
                                                     8192, 1024, 1024);
  gemm_kernel<1, 0><<<dim3(8, 64), 256, 0, stream>>>(xh, nullptr, wvh, nullptr, bv, V, nullptr,
                                                     nullptr, 8192, 1024, 1024);
  vtrans_kernel<<<dim3(128, 16), 256, 0, stream>>>(V, VT);
  attn_kernel<<<dim3(128, 16), 128, 0, stream>>>(Qh, Ql, Kh, VT, prefix, AOh);
  gemm_kernel<1, 2><<<dim3(8, 64), 256, 0, stream>>>(AOh, nullptr, woh, nullptr, bo, nullptr,
                                                     nullptr, out, 8192, 1024, 1024);
}

// Round 8
// 254.848 us; speedup vs baseline: 1.1108x; 1.1108x over previous
//
#include <hip/hip_runtime.h>
#include <stdint.h>

// ---------- types ----------
typedef __attribute__((ext_vector_type(8)))  short          short8;   // 8 x bf16 bits (4 VGPR)
typedef __attribute__((ext_vector_type(8)))  unsigned short u16x8;
typedef __attribute__((ext_vector_type(4)))  unsigned short u16x4;
typedef __attribute__((ext_vector_type(4)))  float          f32x4;
typedef __attribute__((ext_vector_type(16))) float          f32x16;

__device__ __forceinline__ unsigned short f2bf(float x) {
  unsigned int u = __float_as_uint(x);
  u += 0x7fffu + ((u >> 16) & 1u);           // round-to-nearest-even
  return (unsigned short)(u >> 16);
}
__device__ __forceinline__ float bf2f(unsigned short b) {
  return __uint_as_float(((unsigned int)b) << 16);
}

// MFMA via inline asm (gfx950 unified VGPR file)
__device__ __forceinline__ void mfma16(f32x4& c, short8 a, short8 b) {
  asm volatile("v_mfma_f32_16x16x32_bf16 %0, %1, %2, %0" : "+v"(c) : "v"(a), "v"(b));
}
__device__ __forceinline__ void mfma32(f32x16& c, short8 a, short8 b) {
  asm volatile("v_mfma_f32_32x32x16_bf16 %0, %1, %2, %0" : "+v"(c) : "v"(a), "v"(b));
}

// ---------- 1) cast x (fp32 -> bf16 hi plane only; lo plane no longer used) ----------
__global__ void split_x_kernel(const float4* __restrict__ x,
                               ushort4* __restrict__ xh, int n4) {
  int stride = gridDim.x * blockDim.x;
  for (int i = blockIdx.x * blockDim.x + threadIdx.x; i < n4; i += stride) {
    float4 v = x[i];
    ushort4 h;
    h.x = f2bf(v.x);
    h.y = f2bf(v.y);
    h.z = f2bf(v.z);
    h.w = f2bf(v.w);
    xh[i] = h;
  }
}

// ---------- 2) weight transpose + split: W[k][n] fp32 -> WT[n][k] bf16 hi[/lo] ----------
__global__ void wsplit_kernel(const float* __restrict__ Wq, const float* __restrict__ Wk,
                              const float* __restrict__ Wv, const float* __restrict__ Wo,
                              unsigned short* qh, unsigned short* ql,
                              unsigned short* kh, unsigned short* kl,
                              unsigned short* vh, unsigned short* oh) {
  __shared__ float tile[32][33];
  int z = blockIdx.z;
  const float* W = (z == 0) ? Wq : (z == 1) ? Wk : (z == 2) ? Wv : Wo;
  unsigned short* Oh = (z == 0) ? qh : (z == 1) ? kh : (z == 2) ? vh : oh;
  unsigned short* Ol = (z == 0) ? ql : (z == 1) ? kl : nullptr;
  int k0 = blockIdx.y * 32, n0 = blockIdx.x * 32;
  int tx = threadIdx.x & 31, ty = threadIdx.x >> 5;  // 32 x 8
#pragma unroll
  for (int j = 0; j < 4; ++j)
    tile[ty + 8 * j][tx] = W[(size_t)(k0 + ty + 8 * j) * 1024 + n0 + tx];
  __syncthreads();
#pragma unroll
  for (int j = 0; j < 4; ++j) {
    float v = tile[tx][ty + 8 * j];
    unsigned short h = f2bf(v);
    size_t idx = (size_t)(n0 + ty + 8 * j) * 1024 + k0 + tx;
    Oh[idx] = h;
    if (Ol) Ol[idx] = f2bf(v - bf2f(h));
  }
}

// ---------- 3) GEMM: C[M,N] = A[M,K] * B^T[N,K] + bias ----------
// NSPLIT: 1 = Ah*Bh; 2 = Ah*Bh + Ah*Bl (W split only; x-lo term dropped per error
// budget: ~1e-3 Q/K element error -> ~0.011 logit std); 3 = + Al*Bh (full split)
// OUTMODE: 0 = bf16, 1 = bf16 hi/lo pair, 2 = fp32
template <int NSPLIT, int OUTMODE>
__global__ __launch_bounds__(256)
void gemm_kernel(const unsigned short* __restrict__ Ah, const unsigned short* __restrict__ Al,
                 const unsigned short* __restrict__ Bh, const unsigned short* __restrict__ Bl,
                 const float* __restrict__ bias,
                 unsigned short* __restrict__ Ch, unsigned short* __restrict__ Cl,
                 float* __restrict__ Cf, int M, int N, int K) {
  constexpr int NT = (NSPLIT == 3) ? 4 : (NSPLIT == 2) ? 3 : 2;
  __shared__ unsigned short smem[NT * 8192];          // tiles of 128 rows x 64 k (16KB each)
  unsigned short* sAh = smem;
  unsigned short* sBh = smem + 8192;
  unsigned short* sBl = (NSPLIT >= 2) ? smem + 2 * 8192 : smem;
  unsigned short* sAl = (NSPLIT == 3) ? smem + 3 * 8192 : smem;

  int t = threadIdx.x;
  int wid = t >> 6, l = t & 63;
  int wm = wid >> 1, wn = wid & 1;                    // 2x2 waves, 64x64 each
  int bm = blockIdx.y * 128, bn = blockIdx.x * 128;

  f32x4 acc[4][4] = {};

  for (int k0 = 0; k0 < K; k0 += 64) {
    u16x8 ra_h[4], rb_h[4], ra_l[4], rb_l[4];
#pragma unroll
    for (int r = 0; r < 4; ++r) {
      int o = (r * 256 + t) << 4;                     // byte offset in 16KB tile
      int row = o >> 7;                               // 128B rows (64 bf16)
      int col = (o & 127) >> 1;                       // element col
      size_t gA = (size_t)(bm + row) * K + k0 + col;
      size_t gB = (size_t)(bn + row) * K + k0 + col;
      ra_h[r] = *(const u16x8*)(Ah + gA);
      rb_h[r] = *(const u16x8*)(Bh + gB);
      if (NSPLIT >= 2) rb_l[r] = *(const u16x8*)(Bl + gB);
      if (NSPLIT == 3) ra_l[r] = *(const u16x8*)(Al + gA);
    }
    __syncthreads();                                  // previous compute done
#pragma unroll
    for (int r = 0; r < 4; ++r) {
      int o = (r * 256 + t) << 4;
      int row = o >> 7;
      int d = (o ^ ((row & 7) << 4)) >> 1;            // XOR swizzle (bank-conflict fix)
      *(u16x8*)(sAh + d) = ra_h[r];
      *(u16x8*)(sBh + d) = rb_h[r];
      if (NSPLIT >= 2) *(u16x8*)(sBl + d) = rb_l[r];
      if (NSPLIT == 3) *(u16x8*)(sAl + d) = ra_l[r];
    }
    __syncthreads();
#pragma unroll
    for (int kh = 0; kh < 2; ++kh) {
      short8 afh[4], bfh[4], afl[4], bfl[4];
#pragma unroll
      for (int m = 0; m < 4; ++m) {
        int row = wm * 64 + m * 16 + (l & 15);
        int cb = (((l >> 4) * 16 + kh * 64) ^ ((row & 7) << 4)) >> 1;
        afh[m] = *(const short8*)(sAh + row * 64 + cb);
        if (NSPLIT == 3) afl[m] = *(const short8*)(sAl + row * 64 + cb);
      }
#pragma unroll
      for (int n = 0; n < 4; ++n) {
        int row = wn * 64 + n * 16 + (l & 15);
        int cb = (((l >> 4) * 16 + kh * 64) ^ ((row & 7) << 4)) >> 1;
        bfh[n] = *(const short8*)(sBh + row * 64 + cb);
        if (NSPLIT >= 2) bfl[n] = *(const short8*)(sBl + row * 64 + cb);
      }
#pragma unroll
      for (int m = 0; m < 4; ++m)
#pragma unroll
        for (int n = 0; n < 4; ++n) {
          mfma16(acc[m][n], afh[m], bfh[n]);
          if (NSPLIT >= 2) mfma16(acc[m][n], afh[m], bfl[n]);
          if (NSPLIT == 3) mfma16(acc[m][n], afl[m], bfh[n]);
        }
    }
  }
  // epilogue: C row = (l>>4)*4 + r, col = l&15 (guide-verified C/D layout)
#pragma unroll
  for (int m = 0; m < 4; ++m) {
    int grow0 = bm + wm * 64 + m * 16 + (l >> 4) * 4;
#pragma unroll
    for (int n = 0; n < 4; ++n) {
      int gcol = bn + wn * 64 + n * 16 + (l & 15);
      float bs = bias[gcol];
#pragma unroll
      for (int r = 0; r < 4; ++r) {
        float v = acc[m][n][r] + bs;
        size_t idx = (size_t)(grow0 + r) * N + gcol;
        if (OUTMODE == 2) {
          Cf[idx] = v;
        } else {
          unsigned short hv = f2bf(v);
          Ch[idx] = hv;
          if (OUTMODE == 1) Cl[idx] = f2bf(v - bf2f(hv));
        }
      }
    }
  }
}

// ---------- 4) V transpose: V[8192][1024] -> VT[1024][8192] (bf16) ----------
__global__ void vtrans_kernel(const unsigned short* __restrict__ V, unsigned short* __restrict__ VT) {
  __shared__ unsigned short tile[64][65];
  int g0 = blockIdx.x * 64, n0 = blockIdx.y * 64;
  int tx = threadIdx.x & 63, ty = threadIdx.x >> 6;   // 64 x 4
#pragma unroll
  for (int j = 0; j < 16; ++j)
    tile[ty + 4 * j][tx] = V[(size_t)(g0 + ty + 4 * j) * 1024 + n0 + tx];
  __syncthreads();
#pragma unroll
  for (int j = 0; j < 16; ++j)
    VT[(size_t)(n0 + ty + 4 * j) * 8192 + g0 + tx] = tile[tx][ty + 4 * j];
}

// ---------- 5) fused attention: 2-wave blocks, single barrier per tile ----------
// grid = (bh=128, qblock=16): XCD-local K/V (id%8 = bh%8).
// ONE barrier/tile: {issue loads(t+1) -> compute buf[cur] -> ds_write buf[cur^1]
// -> barrier}. Writes target the buffer nobody reads this iteration; the barrier
// publishes them for the next. Halves the per-tile waitcnt-drain cost.
__global__ __launch_bounds__(128)
void attn_kernel(const unsigned short* __restrict__ Qh, const unsigned short* __restrict__ Ql,
                 const unsigned short* __restrict__ Kh,
                 const unsigned short* __restrict__ VT, const int* __restrict__ prefix,
                 unsigned short* __restrict__ AOh) {
  const float NEG = -3.0e38f;
  const float L2E = 1.4426950408889634f;
  __shared__ unsigned short sKh[2][32][66];           // 66 shorts = 33 dwords (odd stride)
  __shared__ unsigned short sV [2][64][34];           // V^T tile [d][k], 17-dword stride

  int bh = blockIdx.x;
  int b = bh >> 4, h = bh & 15;
  int t = threadIdx.x, wid = t >> 6, l = t & 63;
  int qb0 = blockIdx.y * 64;
  int qb = qb0 + wid * 32;
  int P = prefix[b];
  int lq = l & 31, g = l >> 5;
  int q = qb + lq;
  bool qfull = (q < P);
  bool allfull = (P >= qb + 32);                      // wave-uniform: every row full

  // hoist Q^T B-frags (lane = q column), hi/lo
  short8 bqh[4], bql[4];
  {
    size_t base = (size_t)(b * 1024 + q) * 1024 + h * 64 + g * 8;
#pragma unroll
    for (int c = 0; c < 4; ++c) {
      bqh[c] = *(const short8*)(Qh + base + c * 16);
      bql[c] = *(const short8*)(Ql + base + c * 16);
    }
  }

  const unsigned short* KhB = Kh + (size_t)b * 1024 * 1024 + h * 64;
  const unsigned short* VTB = VT + (size_t)(h * 64) * 8192 + b * 1024;

  // staging coords (128 threads): K 32x64 (2 row-passes), V^T 64x32 (2 row-passes)
  int srow = t >> 3, scol = (t & 7) * 8;              // srow 0..15, +16
  int vrow = t >> 2, vcol = (t & 3) * 8;              // vrow 0..31, +32

  int kt0 = (qb0 >= P) ? qb0 : 0;                     // block-uniform start
  int ntiles = (1024 - kt0) >> 5;

  f32x16 o0 = {}, o1 = {};                            // O^T: d rows 0..31 / 32..63, col q
  float mrun = 0.0f, lrun = 0.f;

  u16x8 rkh0, rkh1, rv0, rv1;
  // prologue: stage tile 0
  rkh0 = *(const u16x8*)(KhB + (size_t)(kt0 + srow) * 1024 + scol);
  rkh1 = *(const u16x8*)(KhB + (size_t)(kt0 + srow + 16) * 1024 + scol);
  rv0  = *(const u16x8*)(VTB + (size_t)vrow * 8192 + kt0 + vcol);
  rv1  = *(const u16x8*)(VTB + (size_t)(vrow + 32) * 8192 + kt0 + vcol);
  *(u16x8*)&sKh[0][srow][scol]      = rkh0;
  *(u16x8*)&sKh[0][srow + 16][scol] = rkh1;
  *(u16x8*)&sV [0][vrow][vcol]      = rv0;
  *(u16x8*)&sV [0][vrow + 32][vcol] = rv1;
  __syncthreads();

  int cur = 0;
  for (int i = 0; i < ntiles; ++i) {
    int kt = kt0 + i * 32;
    bool more = (i + 1 < ntiles);
    if (more) {                                       // issue next tile's loads early (T14)
      int ktn = kt + 32;
      rkh0 = *(const u16x8*)(KhB + (size_t)(ktn + srow) * 1024 + scol);
      rkh1 = *(const u16x8*)(KhB + (size_t)(ktn + srow + 16) * 1024 + scol);
      rv0  = *(const u16x8*)(VTB + (size_t)vrow * 8192 + ktn + vcol);
      rv1  = *(const u16x8*)(VTB + (size_t)(vrow + 32) * 8192 + ktn + vcol);
    }

    // wave-uniform: tile contributes nothing for this wave's q-rows
    bool wave_dead = (qb >= P) && (kt + 31 < qb);
    if (!wave_dead) {
      // ---- QK^T on buf cur ----
      f32x16 s = {};
      __builtin_amdgcn_s_setprio(1);
#pragma unroll
      for (int c = 0; c < 4; ++c) {
        short8 ah = *(const short8*)&sKh[cur][lq][g * 8 + c * 16];
        mfma32(s, ah, bqh[c]);
        mfma32(s, ah, bql[c]);
      }
      __builtin_amdgcn_s_setprio(0);

      // mask: only the diagonal tile (kt == qb, not all-full) needs per-element work
      float p[16];
      if (allfull || kt > qb) {
#pragma unroll
        for (int r = 0; r < 16; ++r) p[r] = s[r];
      } else {
#pragma unroll
        for (int r = 0; r < 16; ++r) {
          int k = kt + (r & 3) + 8 * (r >> 2) + 4 * g;
          p[r] = (qfull || k >= q) ? s[r] : NEG;
        }
      }
      // tree max
      float m01 = fmaxf(p[0], p[1]),  m23 = fmaxf(p[2], p[3]);
      float m45 = fmaxf(p[4], p[5]),  m67 = fmaxf(p[6], p[7]);
      float m89 = fmaxf(p[8], p[9]),  mab = fmaxf(p[10], p[11]);
      float mcd = fmaxf(p[12], p[13]), mef = fmaxf(p[14], p[15]);
      float tmax = fmaxf(fmaxf(fmaxf(m01, m23), fmaxf(m45, m67)),
                         fmaxf(fmaxf(m89, mab), fmaxf(mcd, mef)));
      tmax = fmaxf(tmax, __shfl_xor(tmax, 32));
      // defer-max (T13): rescale only when max grew past THR=8
      if (!__all(tmax - mrun <= 8.0f)) {
        float mnew = fmaxf(mrun, tmax);
        float al = exp2f((mrun - mnew) * L2E);
        lrun *= al; o0 *= al; o1 *= al;
        mrun = mnew;
      }
#pragma unroll
      for (int r = 0; r < 16; ++r)
        p[r] = exp2f((p[r] - mrun) * L2E);            // masked: exp2(~-3e38) == 0
      // tree sum
      float s01 = p[0] + p[1],  s23 = p[2] + p[3],  s45 = p[4] + p[5],  s67 = p[6] + p[7];
      float s89 = p[8] + p[9],  sab = p[10] + p[11], scd = p[12] + p[13], sef = p[14] + p[15];
      float psum = ((s01 + s23) + (s45 + s67)) + ((s89 + sab) + (scd + sef));
      psum += __shfl_xor(psum, 32);
      lrun += psum;

      // P -> PV B-frags fully in-register (one shfl_xor(32) per word pair; verified r7)
      unsigned int w0, w1, w2, w3, w4, w5, w6, w7;
      asm("v_cvt_pk_bf16_f32 %0, %1, %2" : "=v"(w0) : "v"(p[0]),  "v"(p[1]));
      asm("v_cvt_pk_bf16_f32 %0, %1, %2" : "=v"(w1) : "v"(p[2]),  "v"(p[3]));
      asm("v_cvt_pk_bf16_f32 %0, %1, %2" : "=v"(w2) : "v"(p[4]),  "v"(p[5]));
      asm("v_cvt_pk_bf16_f32 %0, %1, %2" : "=v"(w3) : "v"(p[6]),  "v"(p[7]));
      asm("v_cvt_pk_bf16_f32 %0, %1, %2" : "=v"(w4) : "v"(p[8]),  "v"(p[9]));
      asm("v_cvt_pk_bf16_f32 %0, %1, %2" : "=v"(w5) : "v"(p[10]), "v"(p[11]));
      asm("v_cvt_pk_bf16_f32 %0, %1, %2" : "=v"(w6) : "v"(p[12]), "v"(p[13]));
      asm("v_cvt_pk_bf16_f32 %0, %1, %2" : "=v"(w7) : "v"(p[14]), "v"(p[15]));
      {
        unsigned int v0 = g ? w0 : w2, r0 = __shfl_xor(v0, 32);
        unsigned int v1 = g ? w1 : w3, r1 = __shfl_xor(v1, 32);
        unsigned int v4 = g ? w4 : w6, r4 = __shfl_xor(v4, 32);
        unsigned int v5 = g ? w5 : w7, r5 = __shfl_xor(v5, 32);
        unsigned int n0 = g ? r0 : w0, n2 = g ? w2 : r0;
        unsigned int n1 = g ? r1 : w1, n3 = g ? w3 : r1;
        unsigned int n4 = g ? r4 : w4, n6 = g ? w6 : r4;
        unsigned int n5 = g ? r5 : w5, n7 = g ? w7 : r5;
        w0 = n0; w1 = n1; w2 = n2; w3 = n3; w4 = n4; w5 = n5; w6 = n6; w7 = n7;
      }
      union { unsigned int u[4]; short8 v; } B0, B1;
      B0.u[0] = w0; B0.u[1] = w1; B0.u[2] = w2; B0.u[3] = w3;   // k = kt + g*8 + 0..7
      B1.u[0] = w4; B1.u[1] = w5; B1.u[2] = w6; B1.u[3] = w7;   // k = kt + 16 + g*8 + 0..7

      // O^T += V^T * P^T (A-frags from staged sV)
      short8 va00 = *(const short8*)&sV[cur][lq][g * 8];
      short8 va01 = *(const short8*)&sV[cur][lq][16 + g * 8];
      short8 va10 = *(const short8*)&sV[cur][32 + lq][g * 8];
      short8 va11 = *(const short8*)&sV[cur][32 + lq][16 + g * 8];
      __builtin_amdgcn_s_setprio(1);
      mfma32(o0, va00, B0.v);
      mfma32(o0, va01, B1.v);
      mfma32(o1, va10, B0.v);
      mfma32(o1, va11, B1.v);
      __builtin_amdgcn_s_setprio(0);
    }

    // write NEXT tile into the buffer nobody reads this iteration
    if (more) {
      *(u16x8*)&sKh[cur ^ 1][srow][scol]      = rkh0;
      *(u16x8*)&sKh[cur ^ 1][srow + 16][scol] = rkh1;
      *(u16x8*)&sV [cur ^ 1][vrow][vcol]      = rv0;
      *(u16x8*)&sV [cur ^ 1][vrow + 32][vcol] = rv1;
    }
    __syncthreads();                                  // single barrier: publish writes
    cur ^= 1;
  }

  // write AO (bf16) in the reference's scrambled layout:
  // AO[b, h*64 + q/16, (q%16)*64 + d]; d = (r&3) + 8*(r>>2) + 4*g -> vectorized per quad
  float inv = 1.0f / lrun;
  size_t obase = (size_t)(b * 1024 + h * 64 + (q >> 4)) * 1024 + (q & 15) * 64;
#pragma unroll
  for (int tt = 0; tt < 4; ++tt) {
    u16x4 w0, w1;
#pragma unroll
    for (int j = 0; j < 4; ++j) {
      w0[j] = f2bf(o0[4 * tt + j] * inv);
      w1[j] = f2bf(o1[4 * tt + j] * inv);
    }
    *(u16x4*)(AOh + obase + 8 * tt + 4 * g)      = w0;
    *(u16x4*)(AOh + obase + 32 + 8 * tt + 4 * g) = w1;
  }
}

// ---------- launch ----------
extern "C" void kernel_launch(void* const* d_in, const int* in_sizes, int n_in,
                              void* d_out, int out_size, void* d_ws, size_t ws_size,
                              hipStream_t stream) {
  (void)in_sizes; (void)n_in; (void)out_size;
  const float* x      = (const float*)d_in[0];
  const int*   prefix = (const int*)d_in[1];
  const float* Wq = (const float*)d_in[2];
  const float* bq = (const float*)d_in[3];
  const float* Wk = (const float*)d_in[4];
  const float* bk = (const float*)d_in[5];
  const float* Wv = (const float*)d_in[6];
  const float* bv = (const float*)d_in[7];
  const float* Wo = (const float*)d_in[8];
  const float* bo = (const float*)d_in[9];
  float* out = (float*)d_out;

  const size_t MBY = 1ull << 20;
  if (ws_size < 144 * MBY) return;
  char* ws = (char*)d_ws;
  unsigned short* xh  = (unsigned short*)(ws + 0 * MBY);
  unsigned short* wqh = (unsigned short*)(ws + 32 * MBY);
  unsigned short* wql = (unsigned short*)(ws + 34 * MBY);
  unsigned short* wkh = (unsigned short*)(ws + 36 * MBY);
  unsigned short* wkl = (unsigned short*)(ws + 38 * MBY);
  unsigned short* wvh = (unsigned short*)(ws + 40 * MBY);
  unsigned short* woh = (unsigned short*)(ws + 44 * MBY);
  unsigned short* Qh  = (unsigned short*)(ws + 48 * MBY);
  unsigned short* Ql  = (unsigned short*)(ws + 64 * MBY);
  unsigned short* Kh  = (unsigned short*)(ws + 80 * MBY);
  unsigned short* V   = (unsigned short*)(ws + 112 * MBY);
  unsigned short* VT  = (unsigned short*)(ws + 128 * MBY);
  unsigned short* AOh = V;    // V dead after vtrans

  split_x_kernel<<<1024, 256, 0, stream>>>((const float4*)x, (ushort4*)xh, 8192 * 1024 / 4);
  wsplit_kernel<<<dim3(32, 32, 4), 256, 0, stream>>>(Wq, Wk, Wv, Wo,
                                                     wqh, wql, wkh, wkl, wvh, woh);
  gemm_kernel<2, 1><<<dim3(8, 64), 256, 0, stream>>>(xh, nullptr, wqh, wql, bq, Qh, Ql, nullptr,
                                                     8192, 1024, 1024);
  gemm_kernel<2, 0><<<dim3(8, 64), 256, 0, stream>>>(xh, nullptr, wkh, wkl, bk, Kh, nullptr,
                                                     nullptr, 8192, 1024, 1024);
  gemm_kernel<1, 0><<<dim3(8, 64), 256, 0, stream>>>(xh, nullptr, wvh, nullptr, bv, V, nullptr,
                                                     nullptr, 8192, 1024, 1024);
  vtrans_kernel<<<dim3(128, 16), 256, 0, stream>>>(V, VT);
  attn_kernel<<<dim3(128, 16), 128, 0, stream>>>(Qh, Ql, Kh, VT, prefix, AOh);
  gemm_kernel<1, 2><<<dim3(8, 64), 256, 0, stream>>>(AOh, nullptr, woh, nullptr, bo, nullptr,
                                                     nullptr, out, 8192, 1024, 1024);
}

// Round 9
// 243.890 us; speedup vs baseline: 1.1608x; 1.0449x over previous
//
#include <hip/hip_runtime.h>
#include <stdint.h>

// ---------- types ----------
typedef __attribute__((ext_vector_type(8)))  short          short8;   // 8 x bf16 bits (4 VGPR)
typedef __attribute__((ext_vector_type(8)))  unsigned short u16x8;
typedef __attribute__((ext_vector_type(4)))  unsigned short u16x4;
typedef __attribute__((ext_vector_type(4)))  float          f32x4;
typedef __attribute__((ext_vector_type(16))) float          f32x16;

__device__ __forceinline__ unsigned short f2bf(float x) {
  unsigned int u = __float_as_uint(x);
  u += 0x7fffu + ((u >> 16) & 1u);           // round-to-nearest-even
  return (unsigned short)(u >> 16);
}
__device__ __forceinline__ float bf2f(unsigned short b) {
  return __uint_as_float(((unsigned int)b) << 16);
}

// MFMA via inline asm (gfx950 unified VGPR file)
__device__ __forceinline__ void mfma16(f32x4& c, short8 a, short8 b) {
  asm volatile("v_mfma_f32_16x16x32_bf16 %0, %1, %2, %0" : "+v"(c) : "v"(a), "v"(b));
}
__device__ __forceinline__ void mfma32(f32x16& c, short8 a, short8 b) {
  asm volatile("v_mfma_f32_32x32x16_bf16 %0, %1, %2, %0" : "+v"(c) : "v"(a), "v"(b));
}

// async global->LDS, 16B per lane; LDS dest is wave-uniform base + lane*16
#define GLDS(gsrc, ldst)                                                    \
  __builtin_amdgcn_global_load_lds(                                         \
      (const __attribute__((address_space(1))) void*)(gsrc),                \
      (__attribute__((address_space(3))) void*)(ldst), 16, 0, 0)

// ---------- 1) cast x (fp32 -> bf16 hi plane only) ----------
__global__ void split_x_kernel(const float4* __restrict__ x,
                               ushort4* __restrict__ xh, int n4) {
  int stride = gridDim.x * blockDim.x;
  for (int i = blockIdx.x * blockDim.x + threadIdx.x; i < n4; i += stride) {
    float4 v = x[i];
    ushort4 h;
    h.x = f2bf(v.x);
    h.y = f2bf(v.y);
    h.z = f2bf(v.z);
    h.w = f2bf(v.w);
    xh[i] = h;
  }
}

// ---------- 2) weight transpose + split: W[k][n] fp32 -> WT[n][k] bf16 hi[/lo] ----------
__global__ void wsplit_kernel(const float* __restrict__ Wq, const float* __restrict__ Wk,
                              const float* __restrict__ Wv, const float* __restrict__ Wo,
                              unsigned short* qh, unsigned short* ql,
                              unsigned short* kh, unsigned short* kl,
                              unsigned short* vh, unsigned short* oh) {
  __shared__ float tile[32][33];
  int z = blockIdx.z;
  const float* W = (z == 0) ? Wq : (z == 1) ? Wk : (z == 2) ? Wv : Wo;
  unsigned short* Oh = (z == 0) ? qh : (z == 1) ? kh : (z == 2) ? vh : oh;
  unsigned short* Ol = (z == 0) ? ql : (z == 1) ? kl : nullptr;
  int k0 = blockIdx.y * 32, n0 = blockIdx.x * 32;
  int tx = threadIdx.x & 31, ty = threadIdx.x >> 5;  // 32 x 8
#pragma unroll
  for (int j = 0; j < 4; ++j)
    tile[ty + 8 * j][tx] = W[(size_t)(k0 + ty + 8 * j) * 1024 + n0 + tx];
  __syncthreads();
#pragma unroll
  for (int j = 0; j < 4; ++j) {
    float v = tile[tx][ty + 8 * j];
    unsigned short h = f2bf(v);
    size_t idx = (size_t)(n0 + ty + 8 * j) * 1024 + k0 + tx;
    Oh[idx] = h;
    if (Ol) Ol[idx] = f2bf(v - bf2f(h));
  }
}

// ---------- 3) GEMM: C[M,N] = A[M,K] * B^T[N,K] + bias ----------
// Staging via global_load_lds width=16 (m97 structure): LDS stays LINEAR,
// the XOR swizzle is applied to the GLOBAL source address (involution within
// each 128B row, permutes whole 16B chunks) -> read side unchanged.
// NSPLIT: 1 = Ah*Bh; 2 = + Ah*Bl (W split); 3 = + Al*Bh (full split)
// OUTMODE: 0 = bf16, 1 = bf16 hi/lo pair, 2 = fp32
template <int NSPLIT, int OUTMODE>
__global__ __launch_bounds__(256)
void gemm_kernel(const unsigned short* __restrict__ Ah, const unsigned short* __restrict__ Al,
                 const unsigned short* __restrict__ Bh, const unsigned short* __restrict__ Bl,
                 const float* __restrict__ bias,
                 unsigned short* __restrict__ Ch, unsigned short* __restrict__ Cl,
                 float* __restrict__ Cf, int M, int N, int K) {
  constexpr int NT = (NSPLIT == 3) ? 4 : (NSPLIT == 2) ? 3 : 2;
  __shared__ unsigned short smem[NT * 8192];          // tiles of 128 rows x 64 k (16KB each)
  unsigned short* sAh = smem;
  unsigned short* sBh = smem + 8192;
  unsigned short* sBl = (NSPLIT >= 2) ? smem + 2 * 8192 : smem;
  unsigned short* sAl = (NSPLIT == 3) ? smem + 3 * 8192 : smem;

  int t = threadIdx.x;
  int wid = t >> 6, l = t & 63;
  int wm = wid >> 1, wn = wid & 1;                    // 2x2 waves, 64x64 each
  int bm = blockIdx.y * 128, bn = blockIdx.x * 128;

  f32x4 acc[4][4] = {};

  for (int k0 = 0; k0 < K; k0 += 64) {
    // issue async global->LDS (linear dest, pre-swizzled source)
#pragma unroll
    for (int r = 0; r < 4; ++r) {
      int o = (r * 256 + t) << 4;                     // linear LDS byte offset in tile
      int row = o >> 7;                               // 128B rows (64 bf16)
      int gce = ((o & 127) ^ ((row & 7) << 4)) >> 1;  // swizzled source col (elements)
      int wb  = (o & ~1023) >> 1;                     // wave-uniform LDS base (elements)
      size_t gA = (size_t)(bm + row) * K + k0 + gce;
      size_t gB = (size_t)(bn + row) * K + k0 + gce;
      GLDS(Ah + gA, sAh + wb);
      GLDS(Bh + gB, sBh + wb);
      if (NSPLIT >= 2) GLDS(Bl + gB, sBl + wb);
      if (NSPLIT == 3) GLDS(Al + gA, sAl + wb);
    }
    __syncthreads();                                  // drains vmcnt -> LDS ready
#pragma unroll
    for (int kh = 0; kh < 2; ++kh) {
      short8 afh[4], bfh[4], afl[4], bfl[4];
#pragma unroll
      for (int m = 0; m < 4; ++m) {
        int row = wm * 64 + m * 16 + (l & 15);
        int cb = (((l >> 4) * 16 + kh * 64) ^ ((row & 7) << 4)) >> 1;
        afh[m] = *(const short8*)(sAh + row * 64 + cb);
        if (NSPLIT == 3) afl[m] = *(const short8*)(sAl + row * 64 + cb);
      }
#pragma unroll
      for (int n = 0; n < 4; ++n) {
        int row = wn * 64 + n * 16 + (l & 15);
        int cb = (((l >> 4) * 16 + kh * 64) ^ ((row & 7) << 4)) >> 1;
        bfh[n] = *(const short8*)(sBh + row * 64 + cb);
        if (NSPLIT >= 2) bfl[n] = *(const short8*)(sBl + row * 64 + cb);
      }
#pragma unroll
      for (int m = 0; m < 4; ++m)
#pragma unroll
        for (int n = 0; n < 4; ++n) {
          mfma16(acc[m][n], afh[m], bfh[n]);
          if (NSPLIT >= 2) mfma16(acc[m][n], afh[m], bfl[n]);
          if (NSPLIT == 3) mfma16(acc[m][n], afl[m], bfh[n]);
        }
    }
    __syncthreads();                                  // all reads done before next writes
  }
  // epilogue: C row = (l>>4)*4 + r, col = l&15 (guide-verified C/D layout)
#pragma unroll
  for (int m = 0; m < 4; ++m) {
    int grow0 = bm + wm * 64 + m * 16 + (l >> 4) * 4;
#pragma unroll
    for (int n = 0; n < 4; ++n) {
      int gcol = bn + wn * 64 + n * 16 + (l & 15);
      float bs = bias[gcol];
#pragma unroll
      for (int r = 0; r < 4; ++r) {
        float v = acc[m][n][r] + bs;
        size_t idx = (size_t)(grow0 + r) * N + gcol;
        if (OUTMODE == 2) {
          Cf[idx] = v;
        } else {
          unsigned short hv = f2bf(v);
          Ch[idx] = hv;
          if (OUTMODE == 1) Cl[idx] = f2bf(v - bf2f(hv));
        }
      }
    }
  }
}

// ---------- 4) V transpose: V[8192][1024] -> VT[1024][8192] (bf16) ----------
__global__ void vtrans_kernel(const unsigned short* __restrict__ V, unsigned short* __restrict__ VT) {
  __shared__ unsigned short tile[64][65];
  int g0 = blockIdx.x * 64, n0 = blockIdx.y * 64;
  int tx = threadIdx.x & 63, ty = threadIdx.x >> 6;   // 64 x 4
#pragma unroll
  for (int j = 0; j < 16; ++j)
    tile[ty + 4 * j][tx] = V[(size_t)(g0 + ty + 4 * j) * 1024 + n0 + tx];
  __syncthreads();
#pragma unroll
  for (int j = 0; j < 16; ++j)
    VT[(size_t)(n0 + ty + 4 * j) * 8192 + g0 + tx] = tile[tx][ty + 4 * j];
}

// ---------- 5) fused attention: 2-wave blocks, single barrier per tile ----------
// (unchanged from round 8 for clean attribution of the GEMM change)
__global__ __launch_bounds__(128)
void attn_kernel(const unsigned short* __restrict__ Qh, const unsigned short* __restrict__ Ql,
                 const unsigned short* __restrict__ Kh,
                 const unsigned short* __restrict__ VT, const int* __restrict__ prefix,
                 unsigned short* __restrict__ AOh) {
  const float NEG = -3.0e38f;
  const float L2E = 1.4426950408889634f;
  __shared__ unsigned short sKh[2][32][66];           // 66 shorts = 33 dwords (odd stride)
  __shared__ unsigned short sV [2][64][34];           // V^T tile [d][k], 17-dword stride

  int bh = blockIdx.x;
  int b = bh >> 4, h = bh & 15;
  int t = threadIdx.x, wid = t >> 6, l = t & 63;
  int qb0 = blockIdx.y * 64;
  int qb = qb0 + wid * 32;
  int P = prefix[b];
  int lq = l & 31, g = l >> 5;
  int q = qb + lq;
  bool qfull = (q < P);
  bool allfull = (P >= qb + 32);                      // wave-uniform: every row full

  // hoist Q^T B-frags (lane = q column), hi/lo
  short8 bqh[4], bql[4];
  {
    size_t base = (size_t)(b * 1024 + q) * 1024 + h * 64 + g * 8;
#pragma unroll
    for (int c = 0; c < 4; ++c) {
      bqh[c] = *(const short8*)(Qh + base + c * 16);
      bql[c] = *(const short8*)(Ql + base + c * 16);
    }
  }

  const unsigned short* KhB = Kh + (size_t)b * 1024 * 1024 + h * 64;
  const unsigned short* VTB = VT + (size_t)(h * 64) * 8192 + b * 1024;

  // staging coords (128 threads): K 32x64 (2 row-passes), V^T 64x32 (2 row-passes)
  int srow = t >> 3, scol = (t & 7) * 8;              // srow 0..15, +16
  int vrow = t >> 2, vcol = (t & 3) * 8;              // vrow 0..31, +32

  int kt0 = (qb0 >= P) ? qb0 : 0;                     // block-uniform start
  int ntiles = (1024 - kt0) >> 5;

  f32x16 o0 = {}, o1 = {};                            // O^T: d rows 0..31 / 32..63, col q
  float mrun = 0.0f, lrun = 0.f;

  u16x8 rkh0, rkh1, rv0, rv1;
  // prologue: stage tile 0
  rkh0 = *(const u16x8*)(KhB + (size_t)(kt0 + srow) * 1024 + scol);
  rkh1 = *(const u16x8*)(KhB + (size_t)(kt0 + srow + 16) * 1024 + scol);
  rv0  = *(const u16x8*)(VTB + (size_t)vrow * 8192 + kt0 + vcol);
  rv1  = *(const u16x8*)(VTB + (size_t)(vrow + 32) * 8192 + kt0 + vcol);
  *(u16x8*)&sKh[0][srow][scol]      = rkh0;
  *(u16x8*)&sKh[0][srow + 16][scol] = rkh1;
  *(u16x8*)&sV [0][vrow][vcol]      = rv0;
  *(u16x8*)&sV [0][vrow + 32][vcol] = rv1;
  __syncthreads();

  int cur = 0;
  for (int i = 0; i < ntiles; ++i) {
    int kt = kt0 + i * 32;
    bool more = (i + 1 < ntiles);
    if (more) {                                       // issue next tile's loads early (T14)
      int ktn = kt + 32;
      rkh0 = *(const u16x8*)(KhB + (size_t)(ktn + srow) * 1024 + scol);
      rkh1 = *(const u16x8*)(KhB + (size_t)(ktn + srow + 16) * 1024 + scol);
      rv0  = *(const u16x8*)(VTB + (size_t)vrow * 8192 + ktn + vcol);
      rv1  = *(const u16x8*)(VTB + (size_t)(vrow + 32) * 8192 + ktn + vcol);
    }

    // wave-uniform: tile contributes nothing for this wave's q-rows
    bool wave_dead = (qb >= P) && (kt + 31 < qb);
    if (!wave_dead) {
      // ---- QK^T on buf cur ----
      f32x16 s = {};
      __builtin_amdgcn_s_setprio(1);
#pragma unroll
      for (int c = 0; c < 4; ++c) {
        short8 ah = *(const short8*)&sKh[cur][lq][g * 8 + c * 16];
        mfma32(s, ah, bqh[c]);
        mfma32(s, ah, bql[c]);
      }
      __builtin_amdgcn_s_setprio(0);

      // mask: only the diagonal tile (kt == qb, not all-full) needs per-element work
      float p[16];
      if (allfull || kt > qb) {
#pragma unroll
        for (int r = 0; r < 16; ++r) p[r] = s[r];
      } else {
#pragma unroll
        for (int r = 0; r < 16; ++r) {
          int k = kt + (r & 3) + 8 * (r >> 2) + 4 * g;
          p[r] = (qfull || k >= q) ? s[r] : NEG;
        }
      }
      // tree max
      float m01 = fmaxf(p[0], p[1]),  m23 = fmaxf(p[2], p[3]);
      float m45 = fmaxf(p[4], p[5]),  m67 = fmaxf(p[6], p[7]);
      float m89 = fmaxf(p[8], p[9]),  mab = fmaxf(p[10], p[11]);
      float mcd = fmaxf(p[12], p[13]), mef = fmaxf(p[14], p[15]);
      float tmax = fmaxf(fmaxf(fmaxf(m01, m23), fmaxf(m45, m67)),
                         fmaxf(fmaxf(m89, mab), fmaxf(mcd, mef)));
      tmax = fmaxf(tmax, __shfl_xor(tmax, 32));
      // defer-max (T13): rescale only when max grew past THR=8
      if (!__all(tmax - mrun <= 8.0f)) {
        float mnew = fmaxf(mrun, tmax);
        float al = exp2f((mrun - mnew) * L2E);
        lrun *= al; o0 *= al; o1 *= al;
        mrun = mnew;
      }
#pragma unroll
      for (int r = 0; r < 16; ++r)
        p[r] = exp2f((p[r] - mrun) * L2E);            // masked: exp2(~-3e38) == 0
      // tree sum
      float s01 = p[0] + p[1],  s23 = p[2] + p[3],  s45 = p[4] + p[5],  s67 = p[6] + p[7];
      float s89 = p[8] + p[9],  sab = p[10] + p[11], scd = p[12] + p[13], sef = p[14] + p[15];
      float psum = ((s01 + s23) + (s45 + s67)) + ((s89 + sab) + (scd + sef));
      psum += __shfl_xor(psum, 32);
      lrun += psum;

      // P -> PV B-frags fully in-register (one shfl_xor(32) per word pair; verified r7)
      unsigned int w0, w1, w2, w3, w4, w5, w6, w7;
      asm("v_cvt_pk_bf16_f32 %0, %1, %2" : "=v"(w0) : "v"(p[0]),  "v"(p[1]));
      asm("v_cvt_pk_bf16_f32 %0, %1, %2" : "=v"(w1) : "v"(p[2]),  "v"(p[3]));
      asm("v_cvt_pk_bf16_f32 %0, %1, %2" : "=v"(w2) : "v"(p[4]),  "v"(p[5]));
      asm("v_cvt_pk_bf16_f32 %0, %1, %2" : "=v"(w3) : "v"(p[6]),  "v"(p[7]));
      asm("v_cvt_pk_bf16_f32 %0, %1, %2" : "=v"(w4) : "v"(p[8]),  "v"(p[9]));
      asm("v_cvt_pk_bf16_f32 %0, %1, %2" : "=v"(w5) : "v"(p[10]), "v"(p[11]));
      asm("v_cvt_pk_bf16_f32 %0, %1, %2" : "=v"(w6) : "v"(p[12]), "v"(p[13]));
      asm("v_cvt_pk_bf16_f32 %0, %1, %2" : "=v"(w7) : "v"(p[14]), "v"(p[15]));
      {
        unsigned int v0 = g ? w0 : w2, r0 = __shfl_xor(v0, 32);
        unsigned int v1 = g ? w1 : w3, r1 = __shfl_xor(v1, 32);
        unsigned int v4 = g ? w4 : w6, r4 = __shfl_xor(v4, 32);
        unsigned int v5 = g ? w5 : w7, r5 = __shfl_xor(v5, 32);
        unsigned int n0 = g ? r0 : w0, n2 = g ? w2 : r0;
        unsigned int n1 = g ? r1 : w1, n3 = g ? w3 : r1;
        unsigned int n4 = g ? r4 : w4, n6 = g ? w6 : r4;
        unsigned int n5 = g ? r5 : w5, n7 = g ? w7 : r5;
        w0 = n0; w1 = n1; w2 = n2; w3 = n3; w4 = n4; w5 = n5; w6 = n6; w7 = n7;
      }
      union { unsigned int u[4]; short8 v; } B0, B1;
      B0.u[0] = w0; B0.u[1] = w1; B0.u[2] = w2; B0.u[3] = w3;   // k = kt + g*8 + 0..7
      B1.u[0] = w4; B1.u[1] = w5; B1.u[2] = w6; B1.u[3] = w7;   // k = kt + 16 + g*8 + 0..7

      // O^T += V^T * P^T (A-frags from staged sV)
      short8 va00 = *(const short8*)&sV[cur][lq][g * 8];
      short8 va01 = *(const short8*)&sV[cur][lq][16 + g * 8];
      short8 va10 = *(const short8*)&sV[cur][32 + lq][g * 8];
      short8 va11 = *(const short8*)&sV[cur][32 + lq][16 + g * 8];
      __builtin_amdgcn_s_setprio(1);
      mfma32(o0, va00, B0.v);
      mfma32(o0, va01, B1.v);
      mfma32(o1, va10, B0.v);
      mfma32(o1, va11, B1.v);
      __builtin_amdgcn_s_setprio(0);
    }

    // write NEXT tile into the buffer nobody reads this iteration
    if (more) {
      *(u16x8*)&sKh[cur ^ 1][srow][scol]      = rkh0;
      *(u16x8*)&sKh[cur ^ 1][srow + 16][scol] = rkh1;
      *(u16x8*)&sV [cur ^ 1][vrow][vcol]      = rv0;
      *(u16x8*)&sV [cur ^ 1][vrow + 32][vcol] = rv1;
    }
    __syncthreads();                                  // single barrier: publish writes
    cur ^= 1;
  }

  // write AO (bf16) in the reference's scrambled layout:
  // AO[b, h*64 + q/16, (q%16)*64 + d]; d = (r&3) + 8*(r>>2) + 4*g -> vectorized per quad
  float inv = 1.0f / lrun;
  size_t obase = (size_t)(b * 1024 + h * 64 + (q >> 4)) * 1024 + (q & 15) * 64;
#pragma unroll
  for (int tt = 0; tt < 4; ++tt) {
    u16x4 w0, w1;
#pragma unroll
    for (int j = 0; j < 4; ++j) {
      w0[j] = f2bf(o0[4 * tt + j] * inv);
      w1[j] = f2bf(o1[4 * tt + j] * inv);
    }
    *(u16x4*)(AOh + obase + 8 * tt + 4 * g)      = w0;
    *(u16x4*)(AOh + obase + 32 + 8 * tt + 4 * g) = w1;
  }
}

// ---------- launch ----------
extern "C" void kernel_launch(void* const* d_in, const int* in_sizes, int n_in,
                              void* d_out, int out_size, void* d_ws, size_t ws_size,
                              hipStream_t stream) {
  (void)in_sizes; (void)n_in; (void)out_size;
  const float* x      = (const float*)d_in[0];
  const int*   prefix = (const int*)d_in[1];
  const float* Wq = (const float*)d_in[2];
  const float* bq = (const float*)d_in[3];
  const float* Wk = (const float*)d_in[4];
  const float* bk = (const float*)d_in[5];
  const float* Wv = (const float*)d_in[6];
  const float* bv = (const float*)d_in[7];
  const float* Wo = (const float*)d_in[8];
  const float* bo = (const float*)d_in[9];
  float* out = (float*)d_out;

  const size_t MBY = 1ull << 20;
  if (ws_size < 144 * MBY) return;
  char* ws = (char*)d_ws;
  unsigned short* xh  = (unsigned short*)(ws + 0 * MBY);
  unsigned short* wqh = (unsigned short*)(ws + 32 * MBY);
  unsigned short* wql = (unsigned short*)(ws + 34 * MBY);
  unsigned short* wkh = (unsigned short*)(ws + 36 * MBY);
  unsigned short* wkl = (unsigned short*)(ws + 38 * MBY);
  unsigned short* wvh = (unsigned short*)(ws + 40 * MBY);
  unsigned short* woh = (unsigned short*)(ws + 44 * MBY);
  unsigned short* Qh  = (unsigned short*)(ws + 48 * MBY);
  unsigned short* Ql  = (unsigned short*)(ws + 64 * MBY);
  unsigned short* Kh  = (unsigned short*)(ws + 80 * MBY);
  unsigned short* V   = (unsigned short*)(ws + 112 * MBY);
  unsigned short* VT  = (unsigned short*)(ws + 128 * MBY);
  unsigned short* AOh = V;    // V dead after vtrans

  split_x_kernel<<<1024, 256, 0, stream>>>((const float4*)x, (ushort4*)xh, 8192 * 1024 / 4);
  wsplit_kernel<<<dim3(32, 32, 4), 256, 0, stream>>>(Wq, Wk, Wv, Wo,
                                                     wqh, wql, wkh, wkl, wvh, woh);
  gemm_kernel<2, 1><<<dim3(8, 64), 256, 0, stream>>>(xh, nullptr, wqh, wql, bq, Qh, Ql, nullptr,
                                                     8192, 1024, 1024);
  gemm_kernel<2, 0><<<dim3(8, 64), 256, 0, stream>>>(xh, nullptr, wkh, wkl, bk, Kh, nullptr,
                                                     nullptr, 8192, 1024, 1024);
  gemm_kernel<1, 0><<<dim3(8, 64), 256, 0, stream>>>(xh, nullptr, wvh, nullptr, bv, V, nullptr,
                                                     nullptr, 8192, 1024, 1024);
  vtrans_kernel<<<dim3(128, 16), 256, 0, stream>>>(V, VT);
  attn_kernel<<<dim3(128, 16), 128, 0, stream>>>(Qh, Ql, Kh, VT, prefix, AOh);
  gemm_kernel<1, 2><<<dim3(8, 64), 256, 0, stream>>>(AOh, nullptr, woh, nullptr, bo, nullptr,
                                                     nullptr, out, 8192, 1024, 1024);
}